// Round 1
// baseline (1649.273 us; speedup 1.0000x reference)
//
#include <hip/hip_runtime.h>

#define N_NODES 50000
#define N_EDGES 1600000
#define D 128

__device__ __forceinline__ float4 fma4(float a, float4 b, float4 c){
  c.x = fmaf(a, b.x, c.x); c.y = fmaf(a, b.y, c.y);
  c.z = fmaf(a, b.z, c.z); c.w = fmaf(a, b.w, c.w);
  return c;
}

// ---------------- preprocessing: degree, norm, CSR build ----------------

__global__ __launch_bounds__(256) void hist_kernel(const int* __restrict__ col, int* __restrict__ deg){
  int e = blockIdx.x*256 + threadIdx.x;
  if (e < N_EDGES) atomicAdd(&deg[col[e]], 1);
}

__global__ __launch_bounds__(256) void dinv_kernel(const int* __restrict__ deg, float* __restrict__ dinv){
  int i = blockIdx.x*256 + threadIdx.x;
  if (i < N_NODES){
    int d = deg[i];
    dinv[i] = (d > 0) ? rsqrtf((float)d) : 0.0f;
  }
}

// single-block exclusive scan over N_NODES degrees -> off[0..N], off[N]=E
__global__ __launch_bounds__(1024) void scan_kernel(const int* __restrict__ deg, int* __restrict__ off){
  __shared__ int part[1024];
  const int t = threadIdx.x;
  const int chunk = (N_NODES + 1023)/1024;
  int b = t*chunk; if (b > N_NODES) b = N_NODES;
  int e = b + chunk; if (e > N_NODES) e = N_NODES;
  int s = 0;
  for (int i=b;i<e;i++) s += deg[i];
  part[t] = s;
  __syncthreads();
  for (int d=1; d<1024; d<<=1){
    int v = (t>=d) ? part[t-d] : 0;
    __syncthreads();
    part[t] += v;
    __syncthreads();
  }
  int run = (t>0) ? part[t-1] : 0;
  for (int i=b;i<e;i++){ off[i] = run; run += deg[i]; }
  if (b < N_NODES && e == N_NODES) off[N_NODES] = run;
}

// csr[slot] = {src_node, norm_w bits}, grouped by destination node
__global__ __launch_bounds__(256) void csr_build_kernel(const int* __restrict__ row, const int* __restrict__ col,
                                                        const float* __restrict__ dinv,
                                                        const int* __restrict__ off, int* __restrict__ cursor,
                                                        int2* __restrict__ csr){
  int e = blockIdx.x*256 + threadIdx.x;
  if (e < N_EDGES){
    int c = col[e], r = row[e];
    int p = atomicAdd(&cursor[c], 1);
    float w = dinv[r]*dinv[c];
    csr[off[c] + p] = make_int2(r, __float_as_int(w));
  }
}

// ---------------- SpMM: out[i] = sum_{e in CSR(i)} w_e * cur[src_e] ----------------
// 32 lanes per node, float4 per lane (128 floats). Gather-only, no atomics.

__global__ __launch_bounds__(256) void spmm_kernel(const float* __restrict__ cur, float* __restrict__ outp,
                                                   const int* __restrict__ off, const int2* __restrict__ csr){
  int g = blockIdx.x*256 + threadIdx.x;
  int lane4 = (g & 31)*4;
  int node = g >> 5;
  if (node >= N_NODES) return;
  int b = off[node], e = off[node+1];
  float4 acc = make_float4(0.f,0.f,0.f,0.f);
  int i = b;
  for (; i+2 <= e; i += 2){
    int2 c0 = csr[i], c1 = csr[i+1];
    float4 v0 = *(const float4*)(cur + (size_t)c0.x*D + lane4);
    float4 v1 = *(const float4*)(cur + (size_t)c1.x*D + lane4);
    acc = fma4(__int_as_float(c0.y), v0, acc);
    acc = fma4(__int_as_float(c1.y), v1, acc);
  }
  if (i < e){
    int2 c0 = csr[i];
    float4 v0 = *(const float4*)(cur + (size_t)c0.x*D + lane4);
    acc = fma4(__int_as_float(c0.y), v0, acc);
  }
  *(float4*)(outp + (size_t)node*D + lane4) = acc;
}

// ---------------- fused layer GEMM: out = relu( sum_k src_k @ W[k] + b ) ----------------
// 64-row x 128-col tile per block, 256 threads, thread = 8 rows x 4 cols.
// W staged in 64-k-row LDS halves (32KB) + X tile (32KB) -> 64KB LDS, 2 blocks/CU.
// NOTE: out may alias s0 — each block reads exactly the rows it writes, and all
// s0 loads (k=0 staging) complete before epilogue stores; rows disjoint across blocks.

template<int NSRC, bool RELU>
__global__ __launch_bounds__(256) void tag_gemm_kernel(const float* s0,
    const float* __restrict__ s1, const float* __restrict__ s2, const float* __restrict__ s3,
    const float* __restrict__ W, const float* __restrict__ bias,
    float* outp){
  __shared__ float Ws[64*D];
  __shared__ float Xs[64*D];
  const int tid = threadIdx.x;
  const int cg = tid & 31;   // column group: cols cg*4 .. cg*4+3
  const int rg = tid >> 5;   // row group: rows rg*8 .. rg*8+7
  const int row0 = blockIdx.x * 64;
  float4 acc[8];
  #pragma unroll
  for (int r=0;r<8;r++) acc[r] = make_float4(0.f,0.f,0.f,0.f);

  #pragma unroll
  for (int k=0;k<NSRC;k++){
    const float* sp = (k==0)?s0:(k==1)?s1:(k==2)?s2:s3;
    __syncthreads();   // protect Xs/Ws from previous iteration's readers
    // stage X tile (64 rows x 128 cols)
    for (int i=tid;i<2048;i+=256){
      int r = i>>5;
      int gr = row0 + r;
      float4 v = make_float4(0.f,0.f,0.f,0.f);
      if (gr < N_NODES) v = *(const float4*)(sp + (size_t)gr*D + (i&31)*4);
      ((float4*)Xs)[i] = v;
    }
    #pragma unroll
    for (int kh=0;kh<2;kh++){
      if (kh) __syncthreads();
      const float4* wsrc = (const float4*)(W + k*16384 + kh*8192);
      for (int i=tid;i<2048;i+=256) ((float4*)Ws)[i] = wsrc[i];
      __syncthreads();
      const float* xrow = &Xs[(rg*8)*D + kh*64];
      for (int kk=0; kk<64; kk+=4){
        float4 wv0 = *(const float4*)&Ws[(kk+0)*D + cg*4];
        float4 wv1 = *(const float4*)&Ws[(kk+1)*D + cg*4];
        float4 wv2 = *(const float4*)&Ws[(kk+2)*D + cg*4];
        float4 wv3 = *(const float4*)&Ws[(kk+3)*D + cg*4];
        #pragma unroll
        for (int r=0;r<8;r++){
          float4 xv = *(const float4*)&xrow[r*D + kk];
          acc[r] = fma4(xv.x, wv0, acc[r]);
          acc[r] = fma4(xv.y, wv1, acc[r]);
          acc[r] = fma4(xv.z, wv2, acc[r]);
          acc[r] = fma4(xv.w, wv3, acc[r]);
        }
      }
    }
  }
  float4 bv = *(const float4*)(bias + cg*4);
  #pragma unroll
  for (int r=0;r<8;r++){
    int gr = row0 + rg*8 + r;
    if (gr < N_NODES){
      float4 o = acc[r];
      o.x += bv.x; o.y += bv.y; o.z += bv.z; o.w += bv.w;
      if (RELU){
        o.x = fmaxf(o.x, 0.f); o.y = fmaxf(o.y, 0.f);
        o.z = fmaxf(o.z, 0.f); o.w = fmaxf(o.w, 0.f);
      }
      *(float4*)(outp + (size_t)gr*D + cg*4) = o;
    }
  }
}

// ---------------- launch ----------------

extern "C" void kernel_launch(void* const* d_in, const int* in_sizes, int n_in,
                              void* d_out, int out_size, void* d_ws, size_t ws_size,
                              hipStream_t stream){
  const float* x  = (const float*)d_in[0];
  const int*   ei = (const int*)d_in[1];
  const float* W1 = (const float*)d_in[2];
  const float* b1 = (const float*)d_in[3];
  const float* W2 = (const float*)d_in[4];
  const float* b2 = (const float*)d_in[5];
  const float* W3 = (const float*)d_in[6];
  const float* b3 = (const float*)d_in[7];
  const float* Wf = (const float*)d_in[8];
  const float* bf = (const float*)d_in[9];
  float* out = (float*)d_out;

  const int* row = ei;            // edge_index[0]
  const int* col = ei + N_EDGES;  // edge_index[1]

  // workspace layout (~116 MB)
  char* w = (char*)d_ws;
  int2* csr   = (int2*)w;   w += (size_t)N_EDGES*8;
  float* A    = (float*)w;  w += (size_t)N_NODES*D*4;
  float* B    = (float*)w;  w += (size_t)N_NODES*D*4;
  float* C    = (float*)w;  w += (size_t)N_NODES*D*4;
  float* Dh   = (float*)w;  w += (size_t)N_NODES*D*4;
  int* deg    = (int*)w;    w += (size_t)N_NODES*4;
  int* cursor = (int*)w;    w += (size_t)N_NODES*4;   // contiguous with deg for one memset
  int* off    = (int*)w;    w += (size_t)(N_NODES+1)*4;
  float* dinv = (float*)w;

  hipMemsetAsync(deg, 0, (size_t)2*N_NODES*4, stream);  // deg + cursor

  const int EB = (N_EDGES + 255)/256;         // 6250
  const int SB = (N_NODES*32 + 255)/256;      // 6250
  const int GB = (N_NODES + 63)/64;           // 782

  hist_kernel<<<EB,256,0,stream>>>(col, deg);
  dinv_kernel<<<(N_NODES+255)/256,256,0,stream>>>(deg, dinv);
  scan_kernel<<<1,1024,0,stream>>>(deg, off);
  csr_build_kernel<<<EB,256,0,stream>>>(row, col, dinv, off, cursor, csr);

  // layer 1
  spmm_kernel<<<SB,256,0,stream>>>(x, B, off, csr);
  spmm_kernel<<<SB,256,0,stream>>>(B, C, off, csr);
  spmm_kernel<<<SB,256,0,stream>>>(C, Dh, off, csr);
  tag_gemm_kernel<4,true><<<GB,256,0,stream>>>(x, B, C, Dh, W1, b1, A);
  // layer 2 (out aliases src0 = A; safe, see kernel comment)
  spmm_kernel<<<SB,256,0,stream>>>(A, B, off, csr);
  spmm_kernel<<<SB,256,0,stream>>>(B, C, off, csr);
  spmm_kernel<<<SB,256,0,stream>>>(C, Dh, off, csr);
  tag_gemm_kernel<4,true><<<GB,256,0,stream>>>(A, B, C, Dh, W2, b2, A);
  // layer 3
  spmm_kernel<<<SB,256,0,stream>>>(A, B, off, csr);
  spmm_kernel<<<SB,256,0,stream>>>(B, C, off, csr);
  spmm_kernel<<<SB,256,0,stream>>>(C, Dh, off, csr);
  tag_gemm_kernel<4,true><<<GB,256,0,stream>>>(A, B, C, Dh, W3, b3, A);
  // final head
  tag_gemm_kernel<1,false><<<GB,256,0,stream>>>(A, nullptr, nullptr, nullptr, Wf, bf, out);
}

// Round 2
// 911.803 us; speedup vs baseline: 1.8088x; 1.8088x over previous
//
#include <hip/hip_runtime.h>

#define N_NODES 50000
#define N_EDGES 1600000
#define D 128

typedef _Float16 f16x8 __attribute__((ext_vector_type(8)));
typedef float f32x4 __attribute__((ext_vector_type(4)));

union HU { uint4 u; f16x8 h; };

// ---------------- preprocessing: degree, norm, CSR build ----------------

__global__ __launch_bounds__(256) void hist_kernel(const int* __restrict__ col, int* __restrict__ deg){
  int e = blockIdx.x*256 + threadIdx.x;
  if (e < N_EDGES) atomicAdd(&deg[col[e]], 1);
}

__global__ __launch_bounds__(256) void dinv_kernel(const int* __restrict__ deg, float* __restrict__ dinv){
  int i = blockIdx.x*256 + threadIdx.x;
  if (i < N_NODES){
    int d = deg[i];
    dinv[i] = (d > 0) ? rsqrtf((float)d) : 0.0f;
  }
}

// single-block exclusive scan over N_NODES degrees -> off[0..N], off[N]=E
__global__ __launch_bounds__(1024) void scan_kernel(const int* __restrict__ deg, int* __restrict__ off){
  __shared__ int part[1024];
  const int t = threadIdx.x;
  const int chunk = (N_NODES + 1023)/1024;
  int b = t*chunk; if (b > N_NODES) b = N_NODES;
  int e = b + chunk; if (e > N_NODES) e = N_NODES;
  int s = 0;
  for (int i=b;i<e;i++) s += deg[i];
  part[t] = s;
  __syncthreads();
  for (int d=1; d<1024; d<<=1){
    int v = (t>=d) ? part[t-d] : 0;
    __syncthreads();
    part[t] += v;
    __syncthreads();
  }
  int run = (t>0) ? part[t-1] : 0;
  for (int i=b;i<e;i++){ off[i] = run; run += deg[i]; }
  if (b < N_NODES && e == N_NODES) off[N_NODES] = run;
}

// csr[slot] = {src_node, norm_w bits}, grouped by destination node
__global__ __launch_bounds__(256) void csr_build_kernel(const int* __restrict__ row, const int* __restrict__ col,
                                                        const float* __restrict__ dinv,
                                                        const int* __restrict__ off, int* __restrict__ cursor,
                                                        int2* __restrict__ csr){
  int e = blockIdx.x*256 + threadIdx.x;
  if (e < N_EDGES){
    int c = col[e], r = row[e];
    int p = atomicAdd(&cursor[c], 1);
    float w = dinv[r]*dinv[c];
    csr[off[c] + p] = make_int2(r, __float_as_int(w));
  }
}

// ---------------- fp32 -> f16 conversions ----------------

// x (N x 128 fp32) -> x16 (f16). 8 elements/thread; grid 3125 x 256 exact.
__global__ __launch_bounds__(256) void cvt_x_kernel(const float* __restrict__ x, ushort* __restrict__ x16){
  int i = blockIdx.x*256 + threadIdx.x;
  const float4* xin = (const float4*)x;
  float4 a = xin[(size_t)i*2], b = xin[(size_t)i*2+1];
  HU o;
  o.h[0]=(_Float16)a.x; o.h[1]=(_Float16)a.y; o.h[2]=(_Float16)a.z; o.h[3]=(_Float16)a.w;
  o.h[4]=(_Float16)b.x; o.h[5]=(_Float16)b.y; o.h[6]=(_Float16)b.z; o.h[7]=(_Float16)b.w;
  ((uint4*)x16)[i] = o.u;
}

// 13 weight matrices (fp32, [k][n] row-major 128x128) -> Wt16 [m][n][k] f16 (transposed).
// grid = 13*4 blocks; block b: matrix m=b>>2, quarter q=b&3.
__global__ __launch_bounds__(256) void cvt_w_kernel(const float* __restrict__ W1, const float* __restrict__ W2,
                                                    const float* __restrict__ W3, const float* __restrict__ Wf,
                                                    ushort* __restrict__ Wt){
  int m = blockIdx.x >> 2, q = blockIdx.x & 3;
  const float* src = (m < 4) ? (W1 + (size_t)m*16384)
                   : (m < 8) ? (W2 + (size_t)(m-4)*16384)
                   : (m < 12)? (W3 + (size_t)(m-8)*16384)
                   : Wf;
  ushort* dst = Wt + (size_t)m*16384;
  for (int it = threadIdx.x; it < 1024; it += 256){
    int idx = q*1024 + it;
    int n  = idx >> 5;
    int k4 = (idx & 31)*4;
    // strided reads (L2/L3-hot after first touch), coalesced 8B writes
    float v0 = src[(size_t)(k4+0)*D + n];
    float v1 = src[(size_t)(k4+1)*D + n];
    float v2 = src[(size_t)(k4+2)*D + n];
    float v3 = src[(size_t)(k4+3)*D + n];
    union { uint2 u; _Float16 h[4]; } o;
    o.h[0]=(_Float16)v0; o.h[1]=(_Float16)v1; o.h[2]=(_Float16)v2; o.h[3]=(_Float16)v3;
    *(uint2*)(dst + (size_t)n*D + k4) = o.u;
  }
}

// ---------------- SpMM (f16): out[i] = sum_{e in CSR(i)} w_e * cur[src_e] ----------------
// 16 lanes per node, uint4 (8 f16) per lane. Gather-only, no atomics. fp32 accumulate.

__global__ __launch_bounds__(256) void spmm16_kernel(const ushort* __restrict__ cur, ushort* __restrict__ outp,
                                                     const int* __restrict__ off, const int2* __restrict__ csr){
  int g = blockIdx.x*256 + threadIdx.x;
  int node = g >> 4;
  if (node >= N_NODES) return;
  int c8 = (g & 15)*8;
  int b = off[node], e = off[node+1];
  float acc[8];
  #pragma unroll
  for (int k=0;k<8;k++) acc[k] = 0.f;
  int i = b;
  for (; i+4 <= e; i += 4){
    int2 c0 = csr[i], c1 = csr[i+1], c2 = csr[i+2], c3 = csr[i+3];
    HU v0, v1, v2, v3;
    v0.u = *(const uint4*)(cur + (size_t)c0.x*D + c8);
    v1.u = *(const uint4*)(cur + (size_t)c1.x*D + c8);
    v2.u = *(const uint4*)(cur + (size_t)c2.x*D + c8);
    v3.u = *(const uint4*)(cur + (size_t)c3.x*D + c8);
    float w0 = __int_as_float(c0.y), w1 = __int_as_float(c1.y);
    float w2 = __int_as_float(c2.y), w3 = __int_as_float(c3.y);
    #pragma unroll
    for (int k=0;k<8;k++){
      acc[k] = fmaf(w0, (float)v0.h[k], acc[k]);
      acc[k] = fmaf(w1, (float)v1.h[k], acc[k]);
      acc[k] = fmaf(w2, (float)v2.h[k], acc[k]);
      acc[k] = fmaf(w3, (float)v3.h[k], acc[k]);
    }
  }
  for (; i < e; i++){
    int2 c0 = csr[i];
    HU v0; v0.u = *(const uint4*)(cur + (size_t)c0.x*D + c8);
    float w0 = __int_as_float(c0.y);
    #pragma unroll
    for (int k=0;k<8;k++) acc[k] = fmaf(w0, (float)v0.h[k], acc[k]);
  }
  HU o;
  #pragma unroll
  for (int k=0;k<8;k++) o.h[k] = (_Float16)acc[k];
  *(uint4*)(outp + (size_t)node*D + c8) = o.u;
}

// ---------------- fused layer GEMM via MFMA f16 ----------------
// out = relu( sum_src S_src @ W_src + b ). Block = 64 rows x 128 cols, 256 threads = 4 waves.
// Wave (wm,wn) computes 32x64 sub-tile: 2 (m) x 4 (n) grid of 16x16 frags, mfma_f32_16x16x32_f16.
// X staged in LDS (padded stride 136 f16 -> 2-way-free banks); B-frags read directly from
// pre-transposed f16 weights Wt[n][k] in global (L2-hot, 16 full lines per wave-load).
// NOTE: out may alias s0 — each block reads exactly the rows it writes (staging), stores in
// epilogue after all reads; rows disjoint across blocks.

template<int NSRC, bool RELU, bool OUTF32>
__global__ __launch_bounds__(256) void gemm_mfma_kernel(const ushort* s0,
    const ushort* __restrict__ s1, const ushort* __restrict__ s2, const ushort* __restrict__ s3,
    const ushort* __restrict__ Wt, const float* __restrict__ bias, void* outp){
  __shared__ ushort Xs[64*136];
  const int tid  = threadIdx.x;
  const int wave = tid >> 6, lane = tid & 63;
  const int quad = lane >> 4, l16 = lane & 15;
  const int wm = wave & 1, wn = wave >> 1;
  const int row0 = blockIdx.x * 64;

  f32x4 acc[2][4];
  #pragma unroll
  for (int i=0;i<2;i++)
    #pragma unroll
    for (int j=0;j<4;j++) acc[i][j] = (f32x4){0.f,0.f,0.f,0.f};

  #pragma unroll
  for (int src=0; src<NSRC; src++){
    const ushort* sp = (src==0)?s0:(src==1)?s1:(src==2)?s2:s3;
    __syncthreads();   // protect Xs from previous iteration's readers
    // stage X tile: 64 rows x 128 f16, 1024 chunks of 8 f16
    for (int i=tid; i<1024; i+=256){
      int r = i >> 4, c = i & 15;
      int gr = row0 + r;
      uint4 v = make_uint4(0u,0u,0u,0u);
      if (gr < N_NODES) v = *(const uint4*)(sp + (size_t)gr*D + c*8);
      *(uint4*)(&Xs[r*136 + c*8]) = v;
    }
    __syncthreads();
    const ushort* wsrc = Wt + (size_t)src*16384;
    #pragma unroll
    for (int ks=0; ks<4; ks++){
      f16x8 a0 = *(const f16x8*)(&Xs[(wm*32 +      l16)*136 + ks*32 + quad*8]);
      f16x8 a1 = *(const f16x8*)(&Xs[(wm*32 + 16 + l16)*136 + ks*32 + quad*8]);
      #pragma unroll
      for (int j=0;j<4;j++){
        f16x8 b = *(const f16x8*)(wsrc + (size_t)(wn*64 + j*16 + l16)*D + ks*32 + quad*8);
        acc[0][j] = __builtin_amdgcn_mfma_f32_16x16x32_f16(a0, b, acc[0][j], 0, 0, 0);
        acc[1][j] = __builtin_amdgcn_mfma_f32_16x16x32_f16(a1, b, acc[1][j], 0, 0, 0);
      }
    }
  }
  // epilogue: bias (+relu), store. C/D layout: col=l16, row=quad*4+reg.
  #pragma unroll
  for (int j=0;j<4;j++){
    int colj = wn*64 + j*16 + l16;
    float bv = bias[colj];
    #pragma unroll
    for (int i=0;i<2;i++){
      int brow = row0 + wm*32 + i*16 + quad*4;
      #pragma unroll
      for (int r=0;r<4;r++){
        int grow = brow + r;
        if (grow < N_NODES){
          float v = acc[i][j][r] + bv;
          if (RELU) v = fmaxf(v, 0.f);
          if (OUTF32) ((float*)outp)[(size_t)grow*D + colj] = v;
          else ((ushort*)outp)[(size_t)grow*D + colj] = __builtin_bit_cast(ushort, (_Float16)v);
        }
      }
    }
  }
}

// ---------------- launch ----------------

extern "C" void kernel_launch(void* const* d_in, const int* in_sizes, int n_in,
                              void* d_out, int out_size, void* d_ws, size_t ws_size,
                              hipStream_t stream){
  const float* x  = (const float*)d_in[0];
  const int*   ei = (const int*)d_in[1];
  const float* W1 = (const float*)d_in[2];
  const float* b1 = (const float*)d_in[3];
  const float* W2 = (const float*)d_in[4];
  const float* b2 = (const float*)d_in[5];
  const float* W3 = (const float*)d_in[6];
  const float* b3 = (const float*)d_in[7];
  const float* Wf = (const float*)d_in[8];
  const float* bf = (const float*)d_in[9];
  float* out = (float*)d_out;

  const int* row = ei;            // edge_index[0]
  const int* col = ei + N_EDGES;  // edge_index[1]

  // workspace layout (~78 MB)
  char* w = (char*)d_ws;
  int2* csr    = (int2*)w;    w += (size_t)N_EDGES*8;
  ushort* x16  = (ushort*)w;  w += (size_t)N_NODES*D*2;
  ushort* A16  = (ushort*)w;  w += (size_t)N_NODES*D*2;
  ushort* B16  = (ushort*)w;  w += (size_t)N_NODES*D*2;
  ushort* C16  = (ushort*)w;  w += (size_t)N_NODES*D*2;
  ushort* D16  = (ushort*)w;  w += (size_t)N_NODES*D*2;
  ushort* Wt   = (ushort*)w;  w += (size_t)13*D*D*2;
  int* deg     = (int*)w;     w += (size_t)N_NODES*4;
  int* cursor  = (int*)w;     w += (size_t)N_NODES*4;   // contiguous with deg for one memset
  int* off     = (int*)w;     w += (size_t)(N_NODES+1)*4;
  float* dinv  = (float*)w;

  hipMemsetAsync(deg, 0, (size_t)2*N_NODES*4, stream);  // deg + cursor

  const int EB  = (N_EDGES + 255)/256;     // 6250
  const int SB  = N_NODES*16/256;          // 3125 (exact)
  const int GB  = (N_NODES + 63)/64;       // 782

  hist_kernel<<<EB,256,0,stream>>>(col, deg);
  dinv_kernel<<<(N_NODES+255)/256,256,0,stream>>>(deg, dinv);
  scan_kernel<<<1,1024,0,stream>>>(deg, off);
  csr_build_kernel<<<EB,256,0,stream>>>(row, col, dinv, off, cursor, csr);
  cvt_x_kernel<<<3125,256,0,stream>>>(x, x16);
  cvt_w_kernel<<<52,256,0,stream>>>(W1, W2, W3, Wf, Wt);

  // layer 1
  spmm16_kernel<<<SB,256,0,stream>>>(x16, B16, off, csr);
  spmm16_kernel<<<SB,256,0,stream>>>(B16, C16, off, csr);
  spmm16_kernel<<<SB,256,0,stream>>>(C16, D16, off, csr);
  gemm_mfma_kernel<4,true,false><<<GB,256,0,stream>>>(x16, B16, C16, D16, Wt + 0*16384, b1, A16);
  // layer 2 (out aliases s0 = A16; safe, see kernel comment)
  spmm16_kernel<<<SB,256,0,stream>>>(A16, B16, off, csr);
  spmm16_kernel<<<SB,256,0,stream>>>(B16, C16, off, csr);
  spmm16_kernel<<<SB,256,0,stream>>>(C16, D16, off, csr);
  gemm_mfma_kernel<4,true,false><<<GB,256,0,stream>>>(A16, B16, C16, D16, Wt + 4*16384, b2, A16);
  // layer 3
  spmm16_kernel<<<SB,256,0,stream>>>(A16, B16, off, csr);
  spmm16_kernel<<<SB,256,0,stream>>>(B16, C16, off, csr);
  spmm16_kernel<<<SB,256,0,stream>>>(C16, D16, off, csr);
  gemm_mfma_kernel<4,true,false><<<GB,256,0,stream>>>(A16, B16, C16, D16, Wt + 8*16384, b3, A16);
  // final head (fp32 out)
  gemm_mfma_kernel<1,false,true><<<GB,256,0,stream>>>(A16, nullptr, nullptr, nullptr, Wt + 12*16384, bf, out);
}

// Round 3
// 864.054 us; speedup vs baseline: 1.9088x; 1.0553x over previous
//
#include <hip/hip_runtime.h>

#define N_NODES 50000
#define N_EDGES 1600000
#define D 128
#define NCHUNK 196   // ceil(N_NODES/256)

typedef _Float16 f16x8 __attribute__((ext_vector_type(8)));
typedef float f32x4 __attribute__((ext_vector_type(4)));

union HU { uint4 u; f16x8 h; };

// ---------------- preprocessing: degree, norm ----------------

__global__ __launch_bounds__(256) void hist_kernel(const int* __restrict__ col, int* __restrict__ deg){
  int e = blockIdx.x*256 + threadIdx.x;
  if (e < N_EDGES) atomicAdd(&deg[col[e]], 1);
}

__global__ __launch_bounds__(256) void dinv_kernel(const int* __restrict__ deg, float* __restrict__ dinv){
  int i = blockIdx.x*256 + threadIdx.x;
  if (i < N_NODES){
    int d = deg[i];
    dinv[i] = (d > 0) ? rsqrtf((float)d) : 0.0f;
  }
}

// ---------------- parallel exclusive scan (3 kernels) ----------------

__global__ __launch_bounds__(256) void scan1_kernel(const int* __restrict__ deg, int* __restrict__ chunkSum){
  __shared__ int red[256];
  int i = blockIdx.x*256 + threadIdx.x;
  red[threadIdx.x] = (i < N_NODES) ? deg[i] : 0;
  __syncthreads();
  for (int d=128; d>0; d>>=1){
    if (threadIdx.x < d) red[threadIdx.x] += red[threadIdx.x+d];
    __syncthreads();
  }
  if (threadIdx.x == 0) chunkSum[blockIdx.x] = red[0];
}

__global__ __launch_bounds__(256) void scan2_kernel(int* __restrict__ chunkSum, int* __restrict__ off){
  __shared__ int part[256];
  int t = threadIdx.x;
  int v = (t < NCHUNK) ? chunkSum[t] : 0;
  part[t] = v;
  __syncthreads();
  for (int d=1; d<256; d<<=1){
    int x = (t>=d) ? part[t-d] : 0;
    __syncthreads();
    part[t] += x;
    __syncthreads();
  }
  if (t < NCHUNK) chunkSum[t] = part[t] - v;   // exclusive chunk base
  if (t == 255) off[N_NODES] = part[255];
}

__global__ __launch_bounds__(256) void scan3_kernel(const int* __restrict__ deg, const int* __restrict__ chunkSum,
                                                    int* __restrict__ off){
  __shared__ int part[256];
  int t = threadIdx.x;
  int i = blockIdx.x*256 + t;
  int v = (i < N_NODES) ? deg[i] : 0;
  part[t] = v;
  __syncthreads();
  for (int d=1; d<256; d<<=1){
    int x = (t>=d) ? part[t-d] : 0;
    __syncthreads();
    part[t] += x;
    __syncthreads();
  }
  if (i < N_NODES) off[i] = chunkSum[blockIdx.x] + part[t] - v;
}

// ---------------- CSR build: 2-byte entries (src only; weights folded into scaled features) ----------------
// 3.2 MB scatter target fits per-XCD L2 -> writebacks merge (vs 103 MB with 8B entries).

__global__ __launch_bounds__(256) void csr_build_kernel(const int* __restrict__ row, const int* __restrict__ col,
                                                        const int* __restrict__ off, int* __restrict__ cursor,
                                                        ushort* __restrict__ csrS){
  int e = blockIdx.x*256 + threadIdx.x;
  if (e < N_EDGES){
    int c = col[e];
    int p = atomicAdd(&cursor[c], 1);
    csrS[off[c] + p] = (ushort)row[e];
  }
}

// ---------------- fp32 -> f16 conversions ----------------

// x -> x16 (f16) and xs16 = dinv*x (scaled gather source). 8 elems/thread; grid 3125x256 exact.
__global__ __launch_bounds__(256) void cvt_x_kernel(const float* __restrict__ x, const float* __restrict__ dinv,
                                                    ushort* __restrict__ x16, ushort* __restrict__ xs16){
  int i = blockIdx.x*256 + threadIdx.x;
  int node = i >> 4;
  float di = dinv[node];
  const float4* xin = (const float4*)x;
  float4 a = xin[(size_t)i*2], b = xin[(size_t)i*2+1];
  HU o, os;
  o.h[0]=(_Float16)a.x; o.h[1]=(_Float16)a.y; o.h[2]=(_Float16)a.z; o.h[3]=(_Float16)a.w;
  o.h[4]=(_Float16)b.x; o.h[5]=(_Float16)b.y; o.h[6]=(_Float16)b.z; o.h[7]=(_Float16)b.w;
  os.h[0]=(_Float16)(di*a.x); os.h[1]=(_Float16)(di*a.y); os.h[2]=(_Float16)(di*a.z); os.h[3]=(_Float16)(di*a.w);
  os.h[4]=(_Float16)(di*b.x); os.h[5]=(_Float16)(di*b.y); os.h[6]=(_Float16)(di*b.z); os.h[7]=(_Float16)(di*b.w);
  ((uint4*)x16)[i]  = o.u;
  ((uint4*)xs16)[i] = os.u;
}

// 13 weight matrices (fp32 [k][n] 128x128) -> Wt16 [m][n][k] f16 (transposed).
__global__ __launch_bounds__(256) void cvt_w_kernel(const float* __restrict__ W1, const float* __restrict__ W2,
                                                    const float* __restrict__ W3, const float* __restrict__ Wf,
                                                    ushort* __restrict__ Wt){
  int m = blockIdx.x >> 2, q = blockIdx.x & 3;
  const float* src = (m < 4) ? (W1 + (size_t)m*16384)
                   : (m < 8) ? (W2 + (size_t)(m-4)*16384)
                   : (m < 12)? (W3 + (size_t)(m-8)*16384)
                   : Wf;
  ushort* dst = Wt + (size_t)m*16384;
  for (int it = threadIdx.x; it < 1024; it += 256){
    int idx = q*1024 + it;
    int n  = idx >> 5;
    int k4 = (idx & 31)*4;
    float v0 = src[(size_t)(k4+0)*D + n];
    float v1 = src[(size_t)(k4+1)*D + n];
    float v2 = src[(size_t)(k4+2)*D + n];
    float v3 = src[(size_t)(k4+3)*D + n];
    union { uint2 u; _Float16 h[4]; } o;
    o.h[0]=(_Float16)v0; o.h[1]=(_Float16)v1; o.h[2]=(_Float16)v2; o.h[3]=(_Float16)v3;
    *(uint2*)(dst + (size_t)n*D + k4) = o.u;
  }
}

// ---------------- SpMM (scaled-feature form) ----------------
// in: sIn = dinv.*h_prev (f16). acc_i = sum_{j->i} sIn_j (pure gather+add, no per-edge weight).
// out: hOut_i = dinv_i * acc_i (GEMM input); sOut_i = dinv_i^2 * acc_i (next hop's gather src).
// 16 lanes/node, uint4 (8 f16) per lane, fp32 accumulate.

template<bool WS>
__global__ __launch_bounds__(256) void spmm16_kernel(const ushort* __restrict__ sIn, ushort* __restrict__ hOut,
                                                     ushort* __restrict__ sOut,
                                                     const int* __restrict__ off, const ushort* __restrict__ csrS,
                                                     const float* __restrict__ dinv){
  int g = blockIdx.x*256 + threadIdx.x;
  int node = g >> 4;
  if (node >= N_NODES) return;
  int c8 = (g & 15)*8;
  int b = off[node], e = off[node+1];
  float acc[8];
  #pragma unroll
  for (int k=0;k<8;k++) acc[k] = 0.f;
  int i = b;
  for (; i+4 <= e; i += 4){
    int s0 = csrS[i], s1 = csrS[i+1], s2 = csrS[i+2], s3 = csrS[i+3];
    HU v0, v1, v2, v3;
    v0.u = *(const uint4*)(sIn + (size_t)s0*D + c8);
    v1.u = *(const uint4*)(sIn + (size_t)s1*D + c8);
    v2.u = *(const uint4*)(sIn + (size_t)s2*D + c8);
    v3.u = *(const uint4*)(sIn + (size_t)s3*D + c8);
    #pragma unroll
    for (int k=0;k<8;k++){
      acc[k] += (float)v0.h[k] + (float)v1.h[k];
      acc[k] += (float)v2.h[k] + (float)v3.h[k];
    }
  }
  for (; i < e; i++){
    int s0 = csrS[i];
    HU v0; v0.u = *(const uint4*)(sIn + (size_t)s0*D + c8);
    #pragma unroll
    for (int k=0;k<8;k++) acc[k] += (float)v0.h[k];
  }
  float di = dinv[node];
  HU oh, os;
  #pragma unroll
  for (int k=0;k<8;k++){
    float h = di*acc[k];
    oh.h[k] = (_Float16)h;
    if (WS) os.h[k] = (_Float16)(di*h);
  }
  *(uint4*)(hOut + (size_t)node*D + c8) = oh.u;
  if (WS) *(uint4*)(sOut + (size_t)node*D + c8) = os.u;
}

// ---------------- fused layer GEMM via MFMA f16 ----------------
// out = relu( sum_src S_src @ W_src + b ); also writes sOut = dinv.*out (next layer's gather src).
// Block = 64 rows x 128 cols, 256 threads = 4 waves; wave (wm,wn) does 32x64 via 2x4 16x16 frags.
// NOTE: out may alias s0 — each block reads exactly the rows it writes (staging), stores after.

template<int NSRC, bool RELU, bool OUTF32, bool WS>
__global__ __launch_bounds__(256) void gemm_mfma_kernel(const ushort* s0,
    const ushort* __restrict__ s1, const ushort* __restrict__ s2, const ushort* __restrict__ s3,
    const ushort* __restrict__ Wt, const float* __restrict__ bias, const float* __restrict__ dinv,
    void* outp, ushort* __restrict__ sOut){
  __shared__ ushort Xs[64*136];
  const int tid  = threadIdx.x;
  const int wave = tid >> 6, lane = tid & 63;
  const int quad = lane >> 4, l16 = lane & 15;
  const int wm = wave & 1, wn = wave >> 1;
  const int row0 = blockIdx.x * 64;

  f32x4 acc[2][4];
  #pragma unroll
  for (int i=0;i<2;i++)
    #pragma unroll
    for (int j=0;j<4;j++) acc[i][j] = (f32x4){0.f,0.f,0.f,0.f};

  #pragma unroll
  for (int src=0; src<NSRC; src++){
    const ushort* sp = (src==0)?s0:(src==1)?s1:(src==2)?s2:s3;
    __syncthreads();
    for (int i=tid; i<1024; i+=256){
      int r = i >> 4, c = i & 15;
      int gr = row0 + r;
      uint4 v = make_uint4(0u,0u,0u,0u);
      if (gr < N_NODES) v = *(const uint4*)(sp + (size_t)gr*D + c*8);
      *(uint4*)(&Xs[r*136 + c*8]) = v;
    }
    __syncthreads();
    const ushort* wsrc = Wt + (size_t)src*16384;
    #pragma unroll
    for (int ks=0; ks<4; ks++){
      f16x8 a0 = *(const f16x8*)(&Xs[(wm*32 +      l16)*136 + ks*32 + quad*8]);
      f16x8 a1 = *(const f16x8*)(&Xs[(wm*32 + 16 + l16)*136 + ks*32 + quad*8]);
      #pragma unroll
      for (int j=0;j<4;j++){
        f16x8 b = *(const f16x8*)(wsrc + (size_t)(wn*64 + j*16 + l16)*D + ks*32 + quad*8);
        acc[0][j] = __builtin_amdgcn_mfma_f32_16x16x32_f16(a0, b, acc[0][j], 0, 0, 0);
        acc[1][j] = __builtin_amdgcn_mfma_f32_16x16x32_f16(a1, b, acc[1][j], 0, 0, 0);
      }
    }
  }
  // epilogue: bias (+relu), store. C/D layout: col=l16, row=quad*4+reg.
  #pragma unroll
  for (int j=0;j<4;j++){
    int colj = wn*64 + j*16 + l16;
    float bv = bias[colj];
    #pragma unroll
    for (int i=0;i<2;i++){
      int brow = row0 + wm*32 + i*16 + quad*4;
      #pragma unroll
      for (int r=0;r<4;r++){
        int grow = brow + r;
        if (grow < N_NODES){
          float v = acc[i][j][r] + bv;
          if (RELU) v = fmaxf(v, 0.f);
          if (OUTF32){
            ((float*)outp)[(size_t)grow*D + colj] = v;
          } else {
            ((ushort*)outp)[(size_t)grow*D + colj] = __builtin_bit_cast(ushort, (_Float16)v);
            if (WS) sOut[(size_t)grow*D + colj] = __builtin_bit_cast(ushort, (_Float16)(dinv[grow]*v));
          }
        }
      }
    }
  }
}

// ---------------- launch ----------------

extern "C" void kernel_launch(void* const* d_in, const int* in_sizes, int n_in,
                              void* d_out, int out_size, void* d_ws, size_t ws_size,
                              hipStream_t stream){
  const float* x  = (const float*)d_in[0];
  const int*   ei = (const int*)d_in[1];
  const float* W1 = (const float*)d_in[2];
  const float* b1 = (const float*)d_in[3];
  const float* W2 = (const float*)d_in[4];
  const float* b2 = (const float*)d_in[5];
  const float* W3 = (const float*)d_in[6];
  const float* b3 = (const float*)d_in[7];
  const float* Wf = (const float*)d_in[8];
  const float* bf = (const float*)d_in[9];
  float* out = (float*)d_out;

  const int* row = ei;            // edge_index[0]
  const int* col = ei + N_EDGES;  // edge_index[1]

  // workspace layout (~107 MB)
  char* w = (char*)d_ws;
  ushort* csrS = (ushort*)w;  w += (size_t)N_EDGES*2;      // 3.2 MB
  ushort* x16  = (ushort*)w;  w += (size_t)N_NODES*D*2;
  ushort* xs16 = (ushort*)w;  w += (size_t)N_NODES*D*2;    // also reused as Dh (hop-3 h) — see aliasing note
  ushort* Ah   = (ushort*)w;  w += (size_t)N_NODES*D*2;
  ushort* As   = (ushort*)w;  w += (size_t)N_NODES*D*2;
  ushort* Bh   = (ushort*)w;  w += (size_t)N_NODES*D*2;
  ushort* Bs   = (ushort*)w;  w += (size_t)N_NODES*D*2;
  ushort* Ch   = (ushort*)w;  w += (size_t)N_NODES*D*2;
  ushort* Cs   = (ushort*)w;  w += (size_t)N_NODES*D*2;
  ushort* Wt   = (ushort*)w;  w += (size_t)13*D*D*2;
  int* deg     = (int*)w;     w += (size_t)N_NODES*4;
  int* cursor  = (int*)w;     w += (size_t)N_NODES*4;      // contiguous with deg for one memset
  int* off     = (int*)w;     w += (size_t)(N_NODES+1)*4;
  int* chunkS  = (int*)w;     w += (size_t)256*4;
  float* dinv  = (float*)w;
  // xs16 is dead after each layer's hop-1 gather; safe to write hop-3 h there.
  ushort* Dh = xs16;

  hipMemsetAsync(deg, 0, (size_t)2*N_NODES*4, stream);  // deg + cursor

  const int EB = (N_EDGES + 255)/256;     // 6250
  const int SB = N_NODES*16/256;          // 3125 (exact)
  const int GB = (N_NODES + 63)/64;       // 782

  hist_kernel<<<EB,256,0,stream>>>(col, deg);
  dinv_kernel<<<NCHUNK,256,0,stream>>>(deg, dinv);
  scan1_kernel<<<NCHUNK,256,0,stream>>>(deg, chunkS);
  scan2_kernel<<<1,256,0,stream>>>(chunkS, off);
  scan3_kernel<<<NCHUNK,256,0,stream>>>(deg, chunkS, off);
  csr_build_kernel<<<EB,256,0,stream>>>(row, col, off, cursor, csrS);
  cvt_x_kernel<<<3125,256,0,stream>>>(x, dinv, x16, xs16);
  cvt_w_kernel<<<52,256,0,stream>>>(W1, W2, W3, Wf, Wt);

  // layer 1
  spmm16_kernel<true ><<<SB,256,0,stream>>>(xs16, Bh, Bs, off, csrS, dinv);
  spmm16_kernel<true ><<<SB,256,0,stream>>>(Bs,   Ch, Cs, off, csrS, dinv);
  spmm16_kernel<false><<<SB,256,0,stream>>>(Cs,   Dh, nullptr, off, csrS, dinv);
  gemm_mfma_kernel<4,true,false,true><<<GB,256,0,stream>>>(x16, Bh, Ch, Dh, Wt+0*16384, b1, dinv, Ah, As);
  // layer 2 (gemm out aliases its s0 = Ah; safe, see kernel comment)
  spmm16_kernel<true ><<<SB,256,0,stream>>>(As, Bh, Bs, off, csrS, dinv);
  spmm16_kernel<true ><<<SB,256,0,stream>>>(Bs, Ch, Cs, off, csrS, dinv);
  spmm16_kernel<false><<<SB,256,0,stream>>>(Cs, Dh, nullptr, off, csrS, dinv);
  gemm_mfma_kernel<4,true,false,true><<<GB,256,0,stream>>>(Ah, Bh, Ch, Dh, Wt+4*16384, b2, dinv, Ah, As);
  // layer 3
  spmm16_kernel<true ><<<SB,256,0,stream>>>(As, Bh, Bs, off, csrS, dinv);
  spmm16_kernel<true ><<<SB,256,0,stream>>>(Bs, Ch, Cs, off, csrS, dinv);
  spmm16_kernel<false><<<SB,256,0,stream>>>(Cs, Dh, nullptr, off, csrS, dinv);
  gemm_mfma_kernel<4,true,false,true><<<GB,256,0,stream>>>(Ah, Bh, Ch, Dh, Wt+8*16384, b3, dinv, Ah, As);
  // final head (fp32 out)
  gemm_mfma_kernel<1,false,true,false><<<GB,256,0,stream>>>(Ah, nullptr, nullptr, nullptr, Wt+12*16384, bf, dinv, out, nullptr);
}

// Round 4
// 783.291 us; speedup vs baseline: 2.1056x; 1.1031x over previous
//
#include <hip/hip_runtime.h>

#define N_NODES 50000
#define N_EDGES 1600000
#define D 128
#define NCHUNK 196            // ceil(N_NODES/256) for scans
#define NBL 1024              // nodes per hist/fill block
#define NODEBLKS 49           // ceil(N_NODES/NBL)
#define NPAD (NODEBLKS*NBL)   // 50176
#define NSEG 8
#define CHUNKS_PER_SEG 50000  // uint4 chunks per segment (E/4/NSEG)

typedef _Float16 f16x8 __attribute__((ext_vector_type(8)));
typedef float f32x4 __attribute__((ext_vector_type(4)));

union HU { uint4 u; f16x8 h; };

// ---------------- preprocessing: node-range-owning scan (NO global atomics) ----------------

// Block (nb, s): stream segment s of col[], LDS-count hits among nodes [nb*NBL, nb*NBL+NBL).
__global__ __launch_bounds__(1024) void histA_kernel(const int* __restrict__ col, uint* __restrict__ C){
  __shared__ uint cnt[NBL];
  const int nb = blockIdx.x, s = blockIdx.y;
  const uint n0 = nb*NBL;
  const int t = threadIdx.x;
  cnt[t] = 0;
  __syncthreads();
  const uint4* cv = (const uint4*)col;
  const int cb = s*CHUNKS_PER_SEG, ce = cb + CHUNKS_PER_SEG;
  for (int c = cb + t; c < ce; c += 1024){
    uint4 v = cv[c];
    unsigned d0 = v.x - n0, d1 = v.y - n0, d2 = v.z - n0, d3 = v.w - n0;
    if (d0 < NBL) atomicAdd(&cnt[d0], 1u);
    if (d1 < NBL) atomicAdd(&cnt[d1], 1u);
    if (d2 < NBL) atomicAdd(&cnt[d2], 1u);
    if (d3 < NBL) atomicAdd(&cnt[d3], 1u);
  }
  __syncthreads();
  C[(size_t)s*NPAD + n0 + t] = cnt[t];
}

__global__ __launch_bounds__(256) void degdinv_kernel(const uint* __restrict__ C, int* __restrict__ deg,
                                                      float* __restrict__ dinv){
  int n = blockIdx.x*256 + threadIdx.x;
  if (n < N_NODES){
    uint sum = 0;
    #pragma unroll
    for (int k=0;k<NSEG;k++) sum += C[(size_t)k*NPAD + n];
    deg[n] = (int)sum;
    dinv[n] = (sum > 0) ? rsqrtf((float)sum) : 0.0f;
  }
}

// ---------------- parallel exclusive scan (3 kernels) over deg -> off ----------------

__global__ __launch_bounds__(256) void scan1_kernel(const int* __restrict__ deg, int* __restrict__ chunkSum){
  __shared__ int red[256];
  int i = blockIdx.x*256 + threadIdx.x;
  red[threadIdx.x] = (i < N_NODES) ? deg[i] : 0;
  __syncthreads();
  for (int d=128; d>0; d>>=1){
    if (threadIdx.x < d) red[threadIdx.x] += red[threadIdx.x+d];
    __syncthreads();
  }
  if (threadIdx.x == 0) chunkSum[blockIdx.x] = red[0];
}

__global__ __launch_bounds__(256) void scan2_kernel(int* __restrict__ chunkSum, int* __restrict__ off){
  __shared__ int part[256];
  int t = threadIdx.x;
  int v = (t < NCHUNK) ? chunkSum[t] : 0;
  part[t] = v;
  __syncthreads();
  for (int d=1; d<256; d<<=1){
    int x = (t>=d) ? part[t-d] : 0;
    __syncthreads();
    part[t] += x;
    __syncthreads();
  }
  if (t < NCHUNK) chunkSum[t] = part[t] - v;   // exclusive chunk base
  if (t == 255) off[N_NODES] = part[255];
}

__global__ __launch_bounds__(256) void scan3_kernel(const int* __restrict__ deg, const int* __restrict__ chunkSum,
                                                    int* __restrict__ off){
  __shared__ int part[256];
  int t = threadIdx.x;
  int i = blockIdx.x*256 + t;
  int v = (i < N_NODES) ? deg[i] : 0;
  part[t] = v;
  __syncthreads();
  for (int d=1; d<256; d<<=1){
    int x = (t>=d) ? part[t-d] : 0;
    __syncthreads();
    part[t] += x;
    __syncthreads();
  }
  if (i < N_NODES) off[i] = chunkSum[blockIdx.x] + part[t] - v;
}

// ---------------- CSR fill: LDS cursors, exact per-(block,segment) bases, no global atomics ----------------
// Block (nb,s) writes only into [off[nb*NBL], off[nb*NBL+NBL)) — a contiguous ~64KB window.

__global__ __launch_bounds__(1024) void fillB_kernel(const int* __restrict__ row, const int* __restrict__ col,
                                                     const int* __restrict__ off, const uint* __restrict__ C,
                                                     ushort* __restrict__ csrS){
  __shared__ uint cur[NBL];
  const int nb = blockIdx.x, s = blockIdx.y;
  const uint n0 = nb*NBL;
  const int t = threadIdx.x;
  const int n = (int)n0 + t;
  uint base = 0;
  if (n < N_NODES){
    base = (uint)off[n];
    for (int k=0;k<s;k++) base += C[(size_t)k*NPAD + n];
  }
  cur[t] = base;
  __syncthreads();
  const uint4* cv = (const uint4*)col;
  const int cb = s*CHUNKS_PER_SEG, ce = cb + CHUNKS_PER_SEG;
  for (int c = cb + t; c < ce; c += 1024){
    uint4 v = cv[c];
    int e = c*4;
    unsigned d0 = v.x - n0, d1 = v.y - n0, d2 = v.z - n0, d3 = v.w - n0;
    if (d0 < NBL){ uint p = atomicAdd(&cur[d0], 1u); csrS[p] = (ushort)row[e+0]; }
    if (d1 < NBL){ uint p = atomicAdd(&cur[d1], 1u); csrS[p] = (ushort)row[e+1]; }
    if (d2 < NBL){ uint p = atomicAdd(&cur[d2], 1u); csrS[p] = (ushort)row[e+2]; }
    if (d3 < NBL){ uint p = atomicAdd(&cur[d3], 1u); csrS[p] = (ushort)row[e+3]; }
  }
}

// ---------------- fp32 -> f16 conversions ----------------

__global__ __launch_bounds__(256) void cvt_x_kernel(const float* __restrict__ x, const float* __restrict__ dinv,
                                                    ushort* __restrict__ x16, ushort* __restrict__ xs16){
  int i = blockIdx.x*256 + threadIdx.x;
  int node = i >> 4;
  float di = dinv[node];
  const float4* xin = (const float4*)x;
  float4 a = xin[(size_t)i*2], b = xin[(size_t)i*2+1];
  HU o, os;
  o.h[0]=(_Float16)a.x; o.h[1]=(_Float16)a.y; o.h[2]=(_Float16)a.z; o.h[3]=(_Float16)a.w;
  o.h[4]=(_Float16)b.x; o.h[5]=(_Float16)b.y; o.h[6]=(_Float16)b.z; o.h[7]=(_Float16)b.w;
  os.h[0]=(_Float16)(di*a.x); os.h[1]=(_Float16)(di*a.y); os.h[2]=(_Float16)(di*a.z); os.h[3]=(_Float16)(di*a.w);
  os.h[4]=(_Float16)(di*b.x); os.h[5]=(_Float16)(di*b.y); os.h[6]=(_Float16)(di*b.z); os.h[7]=(_Float16)(di*b.w);
  ((uint4*)x16)[i]  = o.u;
  ((uint4*)xs16)[i] = os.u;
}

__global__ __launch_bounds__(256) void cvt_w_kernel(const float* __restrict__ W1, const float* __restrict__ W2,
                                                    const float* __restrict__ W3, const float* __restrict__ Wf,
                                                    ushort* __restrict__ Wt){
  int m = blockIdx.x >> 2, q = blockIdx.x & 3;
  const float* src = (m < 4) ? (W1 + (size_t)m*16384)
                   : (m < 8) ? (W2 + (size_t)(m-4)*16384)
                   : (m < 12)? (W3 + (size_t)(m-8)*16384)
                   : Wf;
  ushort* dst = Wt + (size_t)m*16384;
  for (int it = threadIdx.x; it < 1024; it += 256){
    int idx = q*1024 + it;
    int n  = idx >> 5;
    int k4 = (idx & 31)*4;
    float v0 = src[(size_t)(k4+0)*D + n];
    float v1 = src[(size_t)(k4+1)*D + n];
    float v2 = src[(size_t)(k4+2)*D + n];
    float v3 = src[(size_t)(k4+3)*D + n];
    union { uint2 u; _Float16 h[4]; } o;
    o.h[0]=(_Float16)v0; o.h[1]=(_Float16)v1; o.h[2]=(_Float16)v2; o.h[3]=(_Float16)v3;
    *(uint2*)(dst + (size_t)n*D + k4) = o.u;
  }
}

// ---------------- SpMM (scaled-feature form, unroll 8) ----------------

template<bool WS>
__global__ __launch_bounds__(256) void spmm16_kernel(const ushort* __restrict__ sIn, ushort* __restrict__ hOut,
                                                     ushort* __restrict__ sOut,
                                                     const int* __restrict__ off, const ushort* __restrict__ csrS,
                                                     const float* __restrict__ dinv){
  int g = blockIdx.x*256 + threadIdx.x;
  int node = g >> 4;
  if (node >= N_NODES) return;
  int c8 = (g & 15)*8;
  int b = off[node], e = off[node+1];
  float acc[8];
  #pragma unroll
  for (int k=0;k<8;k++) acc[k] = 0.f;
  int i = b;
  for (; i+8 <= e; i += 8){
    int s0 = csrS[i],   s1 = csrS[i+1], s2 = csrS[i+2], s3 = csrS[i+3];
    int s4 = csrS[i+4], s5 = csrS[i+5], s6 = csrS[i+6], s7 = csrS[i+7];
    HU v0, v1, v2, v3, v4, v5, v6, v7;
    v0.u = *(const uint4*)(sIn + (size_t)s0*D + c8);
    v1.u = *(const uint4*)(sIn + (size_t)s1*D + c8);
    v2.u = *(const uint4*)(sIn + (size_t)s2*D + c8);
    v3.u = *(const uint4*)(sIn + (size_t)s3*D + c8);
    v4.u = *(const uint4*)(sIn + (size_t)s4*D + c8);
    v5.u = *(const uint4*)(sIn + (size_t)s5*D + c8);
    v6.u = *(const uint4*)(sIn + (size_t)s6*D + c8);
    v7.u = *(const uint4*)(sIn + (size_t)s7*D + c8);
    #pragma unroll
    for (int k=0;k<8;k++){
      float t0 = (float)v0.h[k] + (float)v1.h[k];
      float t1 = (float)v2.h[k] + (float)v3.h[k];
      float t2 = (float)v4.h[k] + (float)v5.h[k];
      float t3 = (float)v6.h[k] + (float)v7.h[k];
      acc[k] += (t0 + t1) + (t2 + t3);
    }
  }
  for (; i+4 <= e; i += 4){
    int s0 = csrS[i], s1 = csrS[i+1], s2 = csrS[i+2], s3 = csrS[i+3];
    HU v0, v1, v2, v3;
    v0.u = *(const uint4*)(sIn + (size_t)s0*D + c8);
    v1.u = *(const uint4*)(sIn + (size_t)s1*D + c8);
    v2.u = *(const uint4*)(sIn + (size_t)s2*D + c8);
    v3.u = *(const uint4*)(sIn + (size_t)s3*D + c8);
    #pragma unroll
    for (int k=0;k<8;k++)
      acc[k] += ((float)v0.h[k] + (float)v1.h[k]) + ((float)v2.h[k] + (float)v3.h[k]);
  }
  for (; i < e; i++){
    int s0 = csrS[i];
    HU v0; v0.u = *(const uint4*)(sIn + (size_t)s0*D + c8);
    #pragma unroll
    for (int k=0;k<8;k++) acc[k] += (float)v0.h[k];
  }
  float di = dinv[node];
  HU oh, os;
  #pragma unroll
  for (int k=0;k<8;k++){
    float h = di*acc[k];
    oh.h[k] = (_Float16)h;
    if (WS) os.h[k] = (_Float16)(di*h);
  }
  *(uint4*)(hOut + (size_t)node*D + c8) = oh.u;
  if (WS) *(uint4*)(sOut + (size_t)node*D + c8) = os.u;
}

// ---------------- fused layer GEMM via MFMA f16 ----------------
// out = relu( sum_src S_src @ W_src + b ); optionally also sOut = dinv.*out.
// NOTE: out may alias s0 — each block reads exactly the rows it writes (staging), stores after.

template<int NSRC, bool RELU, bool OUTF32, bool WS>
__global__ __launch_bounds__(256) void gemm_mfma_kernel(const ushort* s0,
    const ushort* __restrict__ s1, const ushort* __restrict__ s2, const ushort* __restrict__ s3,
    const ushort* __restrict__ Wt, const float* __restrict__ bias, const float* __restrict__ dinv,
    void* outp, ushort* __restrict__ sOut){
  __shared__ ushort Xs[64*136];
  const int tid  = threadIdx.x;
  const int wave = tid >> 6, lane = tid & 63;
  const int quad = lane >> 4, l16 = lane & 15;
  const int wm = wave & 1, wn = wave >> 1;
  const int row0 = blockIdx.x * 64;

  f32x4 acc[2][4];
  #pragma unroll
  for (int i=0;i<2;i++)
    #pragma unroll
    for (int j=0;j<4;j++) acc[i][j] = (f32x4){0.f,0.f,0.f,0.f};

  #pragma unroll
  for (int src=0; src<NSRC; src++){
    const ushort* sp = (src==0)?s0:(src==1)?s1:(src==2)?s2:s3;
    __syncthreads();
    for (int i=tid; i<1024; i+=256){
      int r = i >> 4, c = i & 15;
      int gr = row0 + r;
      uint4 v = make_uint4(0u,0u,0u,0u);
      if (gr < N_NODES) v = *(const uint4*)(sp + (size_t)gr*D + c*8);
      *(uint4*)(&Xs[r*136 + c*8]) = v;
    }
    __syncthreads();
    const ushort* wsrc = Wt + (size_t)src*16384;
    #pragma unroll
    for (int ks=0; ks<4; ks++){
      f16x8 a0 = *(const f16x8*)(&Xs[(wm*32 +      l16)*136 + ks*32 + quad*8]);
      f16x8 a1 = *(const f16x8*)(&Xs[(wm*32 + 16 + l16)*136 + ks*32 + quad*8]);
      #pragma unroll
      for (int j=0;j<4;j++){
        f16x8 b = *(const f16x8*)(wsrc + (size_t)(wn*64 + j*16 + l16)*D + ks*32 + quad*8);
        acc[0][j] = __builtin_amdgcn_mfma_f32_16x16x32_f16(a0, b, acc[0][j], 0, 0, 0);
        acc[1][j] = __builtin_amdgcn_mfma_f32_16x16x32_f16(a1, b, acc[1][j], 0, 0, 0);
      }
    }
  }
  #pragma unroll
  for (int j=0;j<4;j++){
    int colj = wn*64 + j*16 + l16;
    float bv = bias[colj];
    #pragma unroll
    for (int i=0;i<2;i++){
      int brow = row0 + wm*32 + i*16 + quad*4;
      #pragma unroll
      for (int r=0;r<4;r++){
        int grow = brow + r;
        if (grow < N_NODES){
          float v = acc[i][j][r] + bv;
          if (RELU) v = fmaxf(v, 0.f);
          if (OUTF32){
            ((float*)outp)[(size_t)grow*D + colj] = v;
          } else {
            ((ushort*)outp)[(size_t)grow*D + colj] = __builtin_bit_cast(ushort, (_Float16)v);
            if (WS) sOut[(size_t)grow*D + colj] = __builtin_bit_cast(ushort, (_Float16)(dinv[grow]*v));
          }
        }
      }
    }
  }
}

// ---------------- launch ----------------

extern "C" void kernel_launch(void* const* d_in, const int* in_sizes, int n_in,
                              void* d_out, int out_size, void* d_ws, size_t ws_size,
                              hipStream_t stream){
  const float* x  = (const float*)d_in[0];
  const int*   ei = (const int*)d_in[1];
  const float* W1 = (const float*)d_in[2];
  const float* b1 = (const float*)d_in[3];
  const float* W2 = (const float*)d_in[4];
  const float* b2 = (const float*)d_in[5];
  const float* W3 = (const float*)d_in[6];
  const float* b3 = (const float*)d_in[7];
  const float* Wf = (const float*)d_in[8];
  const float* bf = (const float*)d_in[9];
  float* out = (float*)d_out;

  const int* row = ei;            // edge_index[0]
  const int* col = ei + N_EDGES;  // edge_index[1]

  // workspace layout
  char* w = (char*)d_ws;
  ushort* csrS = (ushort*)w;  w += (size_t)N_EDGES*2;
  ushort* x16  = (ushort*)w;  w += (size_t)N_NODES*D*2;
  ushort* xs16 = (ushort*)w;  w += (size_t)N_NODES*D*2;    // reused as Dh after hop-1 (dead then)
  ushort* Ah   = (ushort*)w;  w += (size_t)N_NODES*D*2;
  ushort* As   = (ushort*)w;  w += (size_t)N_NODES*D*2;
  ushort* Bh   = (ushort*)w;  w += (size_t)N_NODES*D*2;
  ushort* Bs   = (ushort*)w;  w += (size_t)N_NODES*D*2;
  ushort* Ch   = (ushort*)w;  w += (size_t)N_NODES*D*2;
  ushort* Cs   = (ushort*)w;  w += (size_t)N_NODES*D*2;
  ushort* Wt   = (ushort*)w;  w += (size_t)13*D*D*2;
  uint* Cc     = (uint*)w;    w += (size_t)NSEG*NPAD*4;    // per-(segment,node) counts
  int* deg     = (int*)w;     w += (size_t)N_NODES*4;
  int* off     = (int*)w;     w += (size_t)(N_NODES+1)*4;
  int* chunkS  = (int*)w;     w += (size_t)256*4;
  float* dinv  = (float*)w;
  ushort* Dh = xs16;

  const int SB = N_NODES*16/256;          // 3125 (exact)
  const int GB = (N_NODES + 63)/64;       // 782

  histA_kernel<<<dim3(NODEBLKS,NSEG),1024,0,stream>>>(col, Cc);
  degdinv_kernel<<<NCHUNK,256,0,stream>>>(Cc, deg, dinv);
  scan1_kernel<<<NCHUNK,256,0,stream>>>(deg, chunkS);
  scan2_kernel<<<1,256,0,stream>>>(chunkS, off);
  scan3_kernel<<<NCHUNK,256,0,stream>>>(deg, chunkS, off);
  fillB_kernel<<<dim3(NODEBLKS,NSEG),1024,0,stream>>>(row, col, off, Cc, csrS);
  cvt_x_kernel<<<3125,256,0,stream>>>(x, dinv, x16, xs16);
  cvt_w_kernel<<<52,256,0,stream>>>(W1, W2, W3, Wf, Wt);

  // layer 1
  spmm16_kernel<true ><<<SB,256,0,stream>>>(xs16, Bh, Bs, off, csrS, dinv);
  spmm16_kernel<true ><<<SB,256,0,stream>>>(Bs,   Ch, Cs, off, csrS, dinv);
  spmm16_kernel<false><<<SB,256,0,stream>>>(Cs,   Dh, nullptr, off, csrS, dinv);
  gemm_mfma_kernel<4,true,false,true><<<GB,256,0,stream>>>(x16, Bh, Ch, Dh, Wt+0*16384, b1, dinv, Ah, As);
  // layer 2 (gemm out aliases its s0 = Ah; safe)
  spmm16_kernel<true ><<<SB,256,0,stream>>>(As, Bh, Bs, off, csrS, dinv);
  spmm16_kernel<true ><<<SB,256,0,stream>>>(Bs, Ch, Cs, off, csrS, dinv);
  spmm16_kernel<false><<<SB,256,0,stream>>>(Cs, Dh, nullptr, off, csrS, dinv);
  gemm_mfma_kernel<4,true,false,true><<<GB,256,0,stream>>>(Ah, Bh, Ch, Dh, Wt+4*16384, b2, dinv, Ah, As);
  // layer 3
  spmm16_kernel<true ><<<SB,256,0,stream>>>(As, Bh, Bs, off, csrS, dinv);
  spmm16_kernel<true ><<<SB,256,0,stream>>>(Bs, Ch, Cs, off, csrS, dinv);
  spmm16_kernel<false><<<SB,256,0,stream>>>(Cs, Dh, nullptr, off, csrS, dinv);
  gemm_mfma_kernel<4,true,false,true><<<GB,256,0,stream>>>(Ah, Bh, Ch, Dh, Wt+8*16384, b3, dinv, Ah, As);
  // final head (fp32 out)
  gemm_mfma_kernel<1,false,true,false><<<GB,256,0,stream>>>(Ah, nullptr, nullptr, nullptr, Wt+12*16384, bf, dinv, out, nullptr);
}